// Round 6
// baseline (812.945 us; speedup 1.0000x reference)
//
#include <hip/hip_runtime.h>
#include <hip/hip_bf16.h>

#define BB 8
#define NN 4096
#define CIN 32
#define MM 1024
#define KNB 64
#define CAND 1024
#define FPS_T 256
#define ROWS 72     // ushort row stride for H tiles (64 + 8 pad)

typedef __attribute__((ext_vector_type(8))) short  short8;
typedef __attribute__((ext_vector_type(4))) float  f32x4;
typedef __attribute__((ext_vector_type(2))) float  f32x2;

// Exactly-rounded squared distance, numpy accumulation order, no FMA contraction.
__device__ __forceinline__ float sq3(float dx, float dy, float dz) {
    return __fadd_rn(__fadd_rn(__fmul_rn(dx, dx), __fmul_rn(dy, dy)), __fmul_rn(dz, dz));
}

__device__ __forceinline__ unsigned short f2bf(float v) {
    union { __hip_bfloat16 b; unsigned short u; } cv;
    cv.b = __float2bfloat16(v);
    return cv.u;
}
__device__ __forceinline__ float bf2f(unsigned short u) {
    union { unsigned short u; __hip_bfloat16 b; } cv;
    cv.u = u;
    return __bfloat162float(cv.b);
}

static __device__ __forceinline__ f32x4 mfma16(short8 a, short8 b, f32x4 c) {
    return __builtin_amdgcn_mfma_f32_16x16x32_bf16(a, b, c, 0, 0, 0);
}

// One DPP max-combine step on a packed u64 key (rocPRIM wave64 pattern).
template<int CTRL>
__device__ __forceinline__ unsigned long long dpp_maxkey(unsigned long long k) {
    unsigned int lo = (unsigned int)k;
    unsigned int hi = (unsigned int)(k >> 32);
    unsigned int nlo = (unsigned int)__builtin_amdgcn_update_dpp((int)lo, (int)lo, CTRL, 0xF, 0xF, false);
    unsigned int nhi = (unsigned int)__builtin_amdgcn_update_dpp((int)hi, (int)hi, CTRL, 0xF, 0xF, false);
    unsigned long long nk = ((unsigned long long)nhi << 32) | (unsigned long long)nlo;
    return nk > k ? nk : k;
}

// ---------------------------------------------------------------------------
// Kernel 0: convert W1/W2/W3 into MFMA B-fragment-ready bf16 hi/lo planes.
// Frag element: B[k = kstep*32 + (lane>>4)*8 + j][n = tile*16 + (lane&15)]
// idx = (((tile*2 + kstep)*2 + h)*64 + lane)*8 + j,  h: 0=hi 1=lo.
// Layer bases (ushorts): L1=0 (4 tiles), L2=8192 (4 tiles), L3=16384 (8 tiles).
// ---------------------------------------------------------------------------
__global__ __launch_bounds__(256) void prep_kernel(
    const float* __restrict__ W1, const float* __restrict__ W2,
    const float* __restrict__ W3, unsigned short* __restrict__ wf)
{
    int gid = blockIdx.x * 256 + threadIdx.x;   // 0..4095 slots
    const float* W; int K, Ncol, base, slot;
    if (gid < 1024)      { W = W1; K = 35; Ncol = 64;  base = 0;     slot = gid; }
    else if (gid < 2048) { W = W2; K = 64; Ncol = 64;  base = 8192;  slot = gid - 1024; }
    else                 { W = W3; K = 64; Ncol = 128; base = 16384; slot = gid - 2048; }
    int lane = slot & 63, h = (slot >> 6) & 1, kstep = (slot >> 7) & 1, tile = slot >> 8;
    int col = tile * 16 + (lane & 15), quad = lane >> 4;
#pragma unroll
    for (int j = 0; j < 8; ++j) {
        int k = kstep * 32 + quad * 8 + j;
        float wv = (k < K) ? W[k * Ncol + col] : 0.0f;
        unsigned short hi = f2bf(wv);
        unsigned short v = h ? f2bf(wv - bf2f(hi)) : hi;
        wf[base + slot * 8 + j] = v;
    }
}

// ---------------------------------------------------------------------------
// Kernel 1: farthest-point sampling, one block (256 thr = 4 waves) per cloud.
// v6: streams winners to idx_ws as they are produced and publishes progress
// in ready[b] (agent-scope release every 64 iters) so sa_kernel can overlap.
// LDS padded to ~134 KB so sa blocks (29 KB) cannot co-reside on fps CUs.
// ---------------------------------------------------------------------------
__global__ __launch_bounds__(FPS_T) void fps_kernel(
    const float* __restrict__ pos, int* __restrict__ idx_ws,
    unsigned int* __restrict__ ready, float* __restrict__ out)
{
    const int b = blockIdx.x;
    const int t = threadIdx.x;
    __shared__ float4 plds4[NN];
    __shared__ int    chosen[MM];
    __shared__ __align__(16) unsigned long long part[2][FPS_T / 64];
    __shared__ float4 lds_pad[4096];   // occupancy blocker (see guard below)

    const float* P = pos + (size_t)b * NN * 3;
    for (int i = t; i < NN; i += FPS_T) {
        float4 v;
        v.x = P[3 * i]; v.y = P[3 * i + 1]; v.z = P[3 * i + 2]; v.w = 0.0f;
        plds4[i] = v;
    }
    if (t == 0) { chosen[0] = 0; idx_ws[b * MM] = 0; }
    __syncthreads();

    // pair s holds points i0 = t + 512*s (.x) and i0 + 256 (.y)
    f32x2 pxv[8], pyv[8], pzv[8], dminv[8];
#pragma unroll
    for (int s = 0; s < 8; ++s) {
        float4 a = plds4[t + 512 * s];
        float4 c = plds4[t + 512 * s + 256];
        pxv[s] = (f32x2){a.x, c.x};
        pyv[s] = (f32x2){a.y, c.y};
        pzv[s] = (f32x2){a.z, c.z};
        dminv[s] = (f32x2){1e10f, 1e10f};
    }

    int win = 0;
    for (int it = 1; it < MM; ++it) {
        float4 wc = plds4[win];
        const f32x2 lxv = (f32x2){wc.x, wc.x};
        const f32x2 lyv = (f32x2){wc.y, wc.y};
        const f32x2 lzv = (f32x2){wc.z, wc.z};
        float bv = -1.0f;
        int   bi = 0;
#pragma unroll
        for (int s = 0; s < 8; ++s) {
            f32x2 d;
            {
#pragma clang fp contract(off)
                f32x2 dx = pxv[s] - lxv;
                f32x2 dy = pyv[s] - lyv;
                f32x2 dz = pzv[s] - lzv;
                d = dx * dx + dy * dy + dz * dz;   // ((x2+y2)+z2), no FMA
            }
            float m0 = fminf(dminv[s].x, d.x);
            float m1 = fminf(dminv[s].y, d.y);
            dminv[s].x = m0;
            dminv[s].y = m1;
            // strict >: first-max priority; indices ascend (.x before .y)
            if (m0 > bv) { bv = m0; bi = t + 512 * s; }
            if (m1 > bv) { bv = m1; bi = t + 512 * s + 256; }
        }
        // d2 >= 0 so float bits monotone as u32; max key = max d2, tie -> min idx.
        unsigned long long k =
            ((unsigned long long)__float_as_uint(bv) << 32) | (unsigned int)(~bi);
        k = dpp_maxkey<0x111>(k);  // row_shr:1
        k = dpp_maxkey<0x112>(k);  // row_shr:2
        k = dpp_maxkey<0x114>(k);  // row_shr:4
        k = dpp_maxkey<0x118>(k);  // row_shr:8
        k = dpp_maxkey<0x142>(k);  // row_bcast:15
        k = dpp_maxkey<0x143>(k);  // row_bcast:31  -> lane 63 has wave max
        if ((t & 63) == 63) part[it & 1][t >> 6] = k;
        __syncthreads();
        const ulonglong2* pp = (const ulonglong2*)&part[it & 1][0];
        ulonglong2 p01 = pp[0], p23 = pp[1];
        unsigned long long ka = p01.x > p01.y ? p01.x : p01.y;
        unsigned long long kb = p23.x > p23.y ? p23.x : p23.y;
        unsigned long long km = ka > kb ? ka : kb;
        win = (int)(~(unsigned int)km);
        if (t == 0) {
            chosen[it] = win;
            idx_ws[b * MM + it] = win;            // stream winner to global
            if ((it & 63) == 63)                  // publish progress (release)
                __hip_atomic_store(&ready[b], (unsigned int)(it + 1),
                                   __ATOMIC_RELEASE, __HIP_MEMORY_SCOPE_AGENT);
        }
        // parity buffer: no second barrier needed
    }
    __syncthreads();

    for (int m = t; m < MM; m += FPS_T) {
        int mi = chosen[m];
        const int PO = BB * MM * 128;       // pos_out offset (floats)
        const int BO = PO + BB * MM * 3;    // batch_out offset
        int row = b * MM + m;
        float4 c = plds4[mi];
        out[PO + 3 * row + 0] = c.x;
        out[PO + 3 * row + 1] = c.y;
        out[PO + 3 * row + 2] = c.z;
        out[BO + row] = (float)b;
    }
    // Never-taken (chosen[0]==0 always, but runtime-valued): keeps lds_pad
    // alive so this block's LDS footprint excludes sa blocks from fps CUs.
    if (chosen[0] != 0) {
        lds_pad[t] = plds4[t];
        out[t] = lds_pad[t].x;
    }
}

// ---------------------------------------------------------------------------
// Kernel 2: ball query + rank-select top-64 + bf16x3 MFMA MLP + masked max.
// One block (256 thr = 4 waves) per centroid. v6: spin-waits (acquire +
// s_sleep) until fps has published this centroid, overlapping all sa work
// under fps's 600 us shadow. Everything else unchanged from round 5.
// ---------------------------------------------------------------------------
__global__ __launch_bounds__(256, 4) void sa_kernel(
    const float* __restrict__ x, const float* __restrict__ pos,
    const int* __restrict__ idx_ws, const unsigned int* __restrict__ ready,
    const unsigned short* __restrict__ wf,
    const float* __restrict__ b1, const float* __restrict__ b2,
    const float* __restrict__ b3, float* __restrict__ out)
{
    const int bm = blockIdx.x;            // 0..B*M-1
    const int b  = bm >> 10;              // M = 1024
    const int t  = threadIdx.x;
    const int w    = t >> 6;              // wave 0..3
    const int lane = t & 63;

    __shared__ unsigned short HA[2 * 64 * ROWS];   // hi plane, then lo plane
    __shared__ unsigned long long candk[CAND];     // (d2_bits<<32)|idx
    __shared__ int   cnt;
    __shared__ int   sel[KNB];
    __shared__ float red[4][128];

    const float R2 = (float)(0.2 * 0.2);
    const float* P = pos + (size_t)b * NN * 3;

    // ---- wait until fps has published centroid m of cloud b ----
    const unsigned int need = (unsigned int)((bm & (MM - 1)) + 1);
    if (t == 0) {
        while (__hip_atomic_load(&ready[b], __ATOMIC_ACQUIRE,
                                 __HIP_MEMORY_SCOPE_AGENT) < need)
            __builtin_amdgcn_s_sleep(2);
        cnt = 0;
    }
    __syncthreads();

    const int ci = idx_ws[bm];
    const float cx = P[3 * ci], cy = P[3 * ci + 1], cz = P[3 * ci + 2];

    // ---- candidates within radius: wave-ballot compaction ----
    for (int i = t; i < NN; i += 256) {
        float dx = P[3 * i] - cx, dy = P[3 * i + 1] - cy, dz = P[3 * i + 2] - cz;
        float d2 = sq3(dx, dy, dz);
        bool hit = d2 <= R2;
        unsigned long long m = __ballot(hit);
        if (m) {
            int leader = __ffsll((unsigned long long)m) - 1;
            int base = 0;
            if (lane == leader) base = atomicAdd(&cnt, __popcll(m));
            base = __shfl(base, leader);
            if (hit) {
                int p = base + __popcll(m & ((1ull << lane) - 1));
                if (p < CAND)
                    candk[p] = ((unsigned long long)__float_as_uint(d2) << 32)
                             | (unsigned int)i;
            }
        }
    }
    __syncthreads();
    const int n = min(cnt, CAND);
    const int V = min(n, KNB);

    // ---- exact rank selection: u64 key order == (d2, idx) lexicographic ----
    for (int i = t; i < n; i += 256) {
        unsigned long long ki = candk[i];
        int rank = 0;
        for (int j = 0; j < n; ++j)
            rank += (candk[j] < ki) ? 1 : 0;
        if (rank < KNB) sel[rank] = (int)(ki & 0xffffffffu);
    }
    __syncthreads();

    // ---- gather H0 (bf16 hi/lo) + zero k-pad cols 32..63 ----
    // row = 16w + (lane&15); 4 lanes (prt=lane>>4) per row.
    {
        const int row = 16 * w + (lane & 15);
        const int prt = lane >> 4;
        short8 z = {};
        *(short8*)(HA + row * ROWS + 32 + prt * 8) = z;             // hi pad
        *(short8*)(HA + 64 * ROWS + row * ROWS + 32 + prt * 8) = z; // lo pad
        if (row < V) {
            int g = b * NN + sel[row];
            const float4* xr = (const float4*)(x + (size_t)g * CIN + prt * 8);
            float4 v0 = xr[0], v1 = xr[1];
            float vv[8] = {v0.x, v0.y, v0.z, v0.w, v1.x, v1.y, v1.z, v1.w};
            short8 hv, lv;
#pragma unroll
            for (int j = 0; j < 8; ++j) {
                unsigned short h = f2bf(vv[j]);
                hv[j] = (short)h;
                lv[j] = (short)f2bf(vv[j] - bf2f(h));
            }
            *(short8*)(HA + row * ROWS + prt * 8) = hv;
            *(short8*)(HA + 64 * ROWS + row * ROWS + prt * 8) = lv;
            if (prt == 0) {   // rel coords overwrite cols 32..34 (same thread
                int g2 = sel[row];  // that zeroed 32..39: program order safe)
#pragma unroll
                for (int c = 0; c < 3; ++c) {
                    float cc = (c == 0) ? cx : (c == 1) ? cy : cz;
                    float rv = P[3 * g2 + c] - cc;
                    unsigned short h = f2bf(rv);
                    HA[row * ROWS + 32 + c] = h;
                    HA[64 * ROWS + row * ROWS + 32 + c] = f2bf(rv - bf2f(h));
                }
            }
        }
    }
    // no barrier: wave reads only its own strip below

    const int m16  = lane & 15;
    const int quad = lane >> 4;
    const int arow = 16 * w + m16;
    const short8* wf8 = (const short8*)wf;

    // ---- layer 1: H0 @ W1 -> HA in place, relu, bf16x3 ----
    {
        short8 aH[2], aL[2];
        aH[0] = *(const short8*)(HA + arow * ROWS + quad * 8);
        aH[1] = *(const short8*)(HA + arow * ROWS + 32 + quad * 8);
        aL[0] = *(const short8*)(HA + 64 * ROWS + arow * ROWS + quad * 8);
        aL[1] = *(const short8*)(HA + 64 * ROWS + arow * ROWS + 32 + quad * 8);
#pragma unroll
        for (int tile = 0; tile < 4; ++tile) {
            f32x4 acc = {};
#pragma unroll
            for (int ks = 0; ks < 2; ++ks) {
                short8 bH = wf8[((tile * 2 + ks) * 2 + 0) * 64 + lane];
                short8 bL = wf8[((tile * 2 + ks) * 2 + 1) * 64 + lane];
                acc = mfma16(aH[ks], bH, acc);
                acc = mfma16(aH[ks], bL, acc);
                acc = mfma16(aL[ks], bH, acc);
            }
            int col = tile * 16 + m16;
            float bb = b1[col];
#pragma unroll
            for (int i = 0; i < 4; ++i) {
                int grow = 16 * w + quad * 4 + i;
                float v = fmaxf(acc[i] + bb, 0.0f);
                unsigned short h = f2bf(v);
                HA[grow * ROWS + col] = h;
                HA[64 * ROWS + grow * ROWS + col] = f2bf(v - bf2f(h));
            }
        }
    }

    // ---- layer 2: H1 @ W2 -> HA in place, relu ----
    {
        short8 aH[2], aL[2];
        aH[0] = *(const short8*)(HA + arow * ROWS + quad * 8);
        aH[1] = *(const short8*)(HA + arow * ROWS + 32 + quad * 8);
        aL[0] = *(const short8*)(HA + 64 * ROWS + arow * ROWS + quad * 8);
        aL[1] = *(const short8*)(HA + 64 * ROWS + arow * ROWS + 32 + quad * 8);
#pragma unroll
        for (int tile = 0; tile < 4; ++tile) {
            f32x4 acc = {};
#pragma unroll
            for (int ks = 0; ks < 2; ++ks) {
                short8 bH = wf8[1024 + ((tile * 2 + ks) * 2 + 0) * 64 + lane];
                short8 bL = wf8[1024 + ((tile * 2 + ks) * 2 + 1) * 64 + lane];
                acc = mfma16(aH[ks], bH, acc);
                acc = mfma16(aH[ks], bL, acc);
                acc = mfma16(aL[ks], bH, acc);
            }
            int col = tile * 16 + m16;
            float bb = b2[col];
#pragma unroll
            for (int i = 0; i < 4; ++i) {
                int grow = 16 * w + quad * 4 + i;
                float v = fmaxf(acc[i] + bb, 0.0f);
                unsigned short h = f2bf(v);
                HA[grow * ROWS + col] = h;
                HA[64 * ROWS + grow * ROWS + col] = f2bf(v - bf2f(h));
            }
        }
    }

    // ---- layer 3: H2 @ W3 (bias deferred), masked strip-max ----
    {
        short8 aH[2], aL[2];
        aH[0] = *(const short8*)(HA + arow * ROWS + quad * 8);
        aH[1] = *(const short8*)(HA + arow * ROWS + 32 + quad * 8);
        aL[0] = *(const short8*)(HA + 64 * ROWS + arow * ROWS + quad * 8);
        aL[1] = *(const short8*)(HA + 64 * ROWS + arow * ROWS + 32 + quad * 8);
#pragma unroll
        for (int tile = 0; tile < 8; ++tile) {
            f32x4 acc = {};
#pragma unroll
            for (int ks = 0; ks < 2; ++ks) {
                short8 bH = wf8[2048 + ((tile * 2 + ks) * 2 + 0) * 64 + lane];
                short8 bL = wf8[2048 + ((tile * 2 + ks) * 2 + 1) * 64 + lane];
                acc = mfma16(aH[ks], bH, acc);
                acc = mfma16(aH[ks], bL, acc);
                acc = mfma16(aL[ks], bH, acc);
            }
            float mv = -1e10f;
#pragma unroll
            for (int i = 0; i < 4; ++i) {
                int grow = 16 * w + quad * 4 + i;   // neighbor index
                float v = (grow < V) ? acc[i] : -1e10f;
                mv = fmaxf(mv, v);
            }
            mv = fmaxf(mv, __shfl_xor(mv, 16));
            mv = fmaxf(mv, __shfl_xor(mv, 32));
            if (lane < 16) red[w][tile * 16 + lane] = mv;
        }
    }
    __syncthreads();

    if (t < 128) {
        float v = fmaxf(fmaxf(red[0][t], red[1][t]), fmaxf(red[2][t], red[3][t]));
        out[(size_t)bm * 128 + t] = v + b3[t];
    }
}

extern "C" void kernel_launch(void* const* d_in, const int* in_sizes, int n_in,
                              void* d_out, int out_size, void* d_ws, size_t ws_size,
                              hipStream_t stream) {
    const float* x   = (const float*)d_in[0];
    const float* pos = (const float*)d_in[1];
    const float* W1 = (const float*)d_in[3];
    const float* b1 = (const float*)d_in[4];
    const float* W2 = (const float*)d_in[5];
    const float* b2 = (const float*)d_in[6];
    const float* W3 = (const float*)d_in[7];
    const float* b3 = (const float*)d_in[8];
    float* out    = (float*)d_out;
    int*   idx_ws = (int*)d_ws;                                    // 32 KB
    unsigned short* wf = (unsigned short*)((char*)d_ws + 32768);   // 48 KB
    unsigned int* ready = (unsigned int*)((char*)d_ws + 81920);    // 32 B

    hipMemsetAsync(ready, 0, BB * sizeof(unsigned int), stream);
    hipLaunchKernelGGL(fps_kernel, dim3(BB), dim3(FPS_T), 0, stream,
                       pos, idx_ws, ready, out);
    hipLaunchKernelGGL(prep_kernel, dim3(16), dim3(256), 0, stream, W1, W2, W3, wf);
    hipLaunchKernelGGL(sa_kernel, dim3(BB * MM), dim3(256), 0, stream,
                       x, pos, idx_ws, ready, wf, b1, b2, b3, out);
}

// Round 9
// 707.147 us; speedup vs baseline: 1.1496x; 1.1496x over previous
//
#include <hip/hip_runtime.h>
#include <hip/hip_bf16.h>

#define BB 8
#define NN 4096
#define CIN 32
#define MM 1024
#define KNB 64
#define CAND 1024
#define ROWS 72     // ushort row stride for H tiles (64 + 8 pad)
#define GRID 256    // 8 fps + 248 workers; 256 blocks <= 256 CUs at >=1 block/CU
#define NWORK (GRID - 8)

typedef __attribute__((ext_vector_type(8))) short  short8;
typedef __attribute__((ext_vector_type(4))) float  f32x4;
typedef __attribute__((ext_vector_type(2))) float  f32x2;

// Exactly-rounded squared distance, numpy accumulation order, no FMA contraction.
__device__ __forceinline__ float sq3(float dx, float dy, float dz) {
    return __fadd_rn(__fadd_rn(__fmul_rn(dx, dx), __fmul_rn(dy, dy)), __fmul_rn(dz, dz));
}

__device__ __forceinline__ unsigned short f2bf(float v) {
    union { __hip_bfloat16 b; unsigned short u; } cv;
    cv.b = __float2bfloat16(v);
    return cv.u;
}
__device__ __forceinline__ float bf2f(unsigned short u) {
    union { unsigned short u; __hip_bfloat16 b; } cv;
    cv.u = u;
    return __bfloat162float(cv.b);
}

static __device__ __forceinline__ f32x4 mfma16(short8 a, short8 b, f32x4 c) {
    return __builtin_amdgcn_mfma_f32_16x16x32_bf16(a, b, c, 0, 0, 0);
}

// One DPP max-combine step on a packed u64 key (rocPRIM wave64 pattern).
template<int CTRL>
__device__ __forceinline__ unsigned long long dpp_maxkey(unsigned long long k) {
    unsigned int lo = (unsigned int)k;
    unsigned int hi = (unsigned int)(k >> 32);
    unsigned int nlo = (unsigned int)__builtin_amdgcn_update_dpp((int)lo, (int)lo, CTRL, 0xF, 0xF, false);
    unsigned int nhi = (unsigned int)__builtin_amdgcn_update_dpp((int)hi, (int)hi, CTRL, 0xF, 0xF, false);
    unsigned long long nk = ((unsigned long long)nhi << 32) | (unsigned long long)nlo;
    return nk > k ? nk : k;
}

// ---------------------------------------------------------------------------
// Kernel 0: convert W1/W2/W3 into MFMA B-fragment-ready bf16 hi/lo planes.
// wf occupies ushort[0..32767] = 65536 B.  (r7/r8 crash root cause: ready[]
// was placed INSIDE this region and got overwritten by prep -> garbage gate
// -> poisoned idx_ws read -> OOB fault. Offsets now disjoint.)
// ---------------------------------------------------------------------------
__global__ __launch_bounds__(256) void prep_kernel(
    const float* __restrict__ W1, const float* __restrict__ W2,
    const float* __restrict__ W3, unsigned short* __restrict__ wf)
{
    int gid = blockIdx.x * 256 + threadIdx.x;   // 0..4095 slots
    const float* W; int K, Ncol, base, slot;
    if (gid < 1024)      { W = W1; K = 35; Ncol = 64;  base = 0;     slot = gid; }
    else if (gid < 2048) { W = W2; K = 64; Ncol = 64;  base = 8192;  slot = gid - 1024; }
    else                 { W = W3; K = 64; Ncol = 128; base = 16384; slot = gid - 2048; }
    int lane = slot & 63, h = (slot >> 6) & 1, kstep = (slot >> 7) & 1, tile = slot >> 8;
    int col = tile * 16 + (lane & 15), quad = lane >> 4;
#pragma unroll
    for (int j = 0; j < 8; ++j) {
        int k = kstep * 32 + quad * 8 + j;
        float wv = (k < K) ? W[k * Ncol + col] : 0.0f;
        unsigned short hi = f2bf(wv);
        unsigned short v = h ? f2bf(wv - bf2f(hi)) : hi;
        wf[base + slot * 8 + j] = v;
    }
}

// ---------------------------------------------------------------------------
// Shared sa state + the full per-centroid body (ball query -> rank-select ->
// bf16x3 MFMA MLP -> masked max). Used by both the fused worker path and the
// sweep kernel.
// ---------------------------------------------------------------------------
struct SaShared {
    unsigned short HA[2 * 64 * ROWS];       // hi plane, then lo plane
    unsigned long long candk[CAND];         // (d2_bits<<32)|idx
    int   cnt;
    int   ok;
    int   sel[KNB];
    float red[4][128];
};

__device__ __forceinline__ void sa_process(
    SaShared& sh, const float* __restrict__ x, const float* __restrict__ P,
    const unsigned short* __restrict__ wf,
    const float* __restrict__ b1, const float* __restrict__ b2,
    const float* __restrict__ b3, float* __restrict__ out, int bm, int b, int ci)
{
    const int t    = threadIdx.x;
    const int w    = t >> 6;
    const int lane = t & 63;
    const float R2 = (float)(0.2 * 0.2);

    if (t == 0) sh.cnt = 0;
    __syncthreads();

    const float cx = P[3 * ci], cy = P[3 * ci + 1], cz = P[3 * ci + 2];

    // ---- candidates within radius: wave-ballot compaction ----
    for (int i = t; i < NN; i += 256) {
        float dx = P[3 * i] - cx, dy = P[3 * i + 1] - cy, dz = P[3 * i + 2] - cz;
        float d2 = sq3(dx, dy, dz);
        bool hit = d2 <= R2;
        unsigned long long mk = __ballot(hit);
        if (mk) {
            int leader = __ffsll((unsigned long long)mk) - 1;
            int base = 0;
            if (lane == leader) base = atomicAdd(&sh.cnt, __popcll(mk));
            base = __shfl(base, leader);
            if (hit) {
                int p = base + __popcll(mk & ((1ull << lane) - 1));
                if (p < CAND)
                    sh.candk[p] = ((unsigned long long)__float_as_uint(d2) << 32)
                                | (unsigned int)i;
            }
        }
    }
    __syncthreads();
    const int n = min(sh.cnt, CAND);
    const int V = min(n, KNB);

    // ---- exact rank selection: u64 key order == (d2, idx) lexicographic ----
    for (int i = t; i < n; i += 256) {
        unsigned long long ki = sh.candk[i];
        int rank = 0;
        for (int j = 0; j < n; ++j)
            rank += (sh.candk[j] < ki) ? 1 : 0;
        if (rank < KNB) sh.sel[rank] = (int)(ki & 0xffffffffu);
    }
    __syncthreads();

    // ---- gather H0 (bf16 hi/lo) + zero k-pad cols 32..63 ----
    {
        const int row = 16 * w + (lane & 15);
        const int prt = lane >> 4;
        short8 z = {};
        *(short8*)(sh.HA + row * ROWS + 32 + prt * 8) = z;             // hi pad
        *(short8*)(sh.HA + 64 * ROWS + row * ROWS + 32 + prt * 8) = z; // lo pad
        if (row < V) {
            int g = b * NN + sh.sel[row];
            const float4* xr = (const float4*)(x + (size_t)g * CIN + prt * 8);
            float4 v0 = xr[0], v1 = xr[1];
            float vv[8] = {v0.x, v0.y, v0.z, v0.w, v1.x, v1.y, v1.z, v1.w};
            short8 hv, lv;
#pragma unroll
            for (int j = 0; j < 8; ++j) {
                unsigned short h = f2bf(vv[j]);
                hv[j] = (short)h;
                lv[j] = (short)f2bf(vv[j] - bf2f(h));
            }
            *(short8*)(sh.HA + row * ROWS + prt * 8) = hv;
            *(short8*)(sh.HA + 64 * ROWS + row * ROWS + prt * 8) = lv;
            if (prt == 0) {   // rel coords overwrite cols 32..34
                int g2 = sh.sel[row];
#pragma unroll
                for (int c = 0; c < 3; ++c) {
                    float cc = (c == 0) ? cx : (c == 1) ? cy : cz;
                    float rv = P[3 * g2 + c] - cc;
                    unsigned short h = f2bf(rv);
                    sh.HA[row * ROWS + 32 + c] = h;
                    sh.HA[64 * ROWS + row * ROWS + 32 + c] = f2bf(rv - bf2f(h));
                }
            }
        }
    }
    // no barrier: each wave reads only its own 16-row strip below

    const int m16  = lane & 15;
    const int quad = lane >> 4;
    const int arow = 16 * w + m16;
    const short8* wf8 = (const short8*)wf;

    // ---- layer 1: H0 @ W1 -> HA in place, relu, bf16x3 ----
    {
        short8 aH[2], aL[2];
        aH[0] = *(const short8*)(sh.HA + arow * ROWS + quad * 8);
        aH[1] = *(const short8*)(sh.HA + arow * ROWS + 32 + quad * 8);
        aL[0] = *(const short8*)(sh.HA + 64 * ROWS + arow * ROWS + quad * 8);
        aL[1] = *(const short8*)(sh.HA + 64 * ROWS + arow * ROWS + 32 + quad * 8);
#pragma unroll
        for (int tile = 0; tile < 4; ++tile) {
            f32x4 acc = {};
#pragma unroll
            for (int ks = 0; ks < 2; ++ks) {
                short8 bH = wf8[((tile * 2 + ks) * 2 + 0) * 64 + lane];
                short8 bL = wf8[((tile * 2 + ks) * 2 + 1) * 64 + lane];
                acc = mfma16(aH[ks], bH, acc);
                acc = mfma16(aH[ks], bL, acc);
                acc = mfma16(aL[ks], bH, acc);
            }
            int col = tile * 16 + m16;
            float bb = b1[col];
#pragma unroll
            for (int i = 0; i < 4; ++i) {
                int grow = 16 * w + quad * 4 + i;
                float v = fmaxf(acc[i] + bb, 0.0f);
                unsigned short h = f2bf(v);
                sh.HA[grow * ROWS + col] = h;
                sh.HA[64 * ROWS + grow * ROWS + col] = f2bf(v - bf2f(h));
            }
        }
    }

    // ---- layer 2: H1 @ W2 -> HA in place, relu ----
    {
        short8 aH[2], aL[2];
        aH[0] = *(const short8*)(sh.HA + arow * ROWS + quad * 8);
        aH[1] = *(const short8*)(sh.HA + arow * ROWS + 32 + quad * 8);
        aL[0] = *(const short8*)(sh.HA + 64 * ROWS + arow * ROWS + quad * 8);
        aL[1] = *(const short8*)(sh.HA + 64 * ROWS + arow * ROWS + 32 + quad * 8);
#pragma unroll
        for (int tile = 0; tile < 4; ++tile) {
            f32x4 acc = {};
#pragma unroll
            for (int ks = 0; ks < 2; ++ks) {
                short8 bH = wf8[1024 + ((tile * 2 + ks) * 2 + 0) * 64 + lane];
                short8 bL = wf8[1024 + ((tile * 2 + ks) * 2 + 1) * 64 + lane];
                acc = mfma16(aH[ks], bH, acc);
                acc = mfma16(aH[ks], bL, acc);
                acc = mfma16(aL[ks], bH, acc);
            }
            int col = tile * 16 + m16;
            float bb = b2[col];
#pragma unroll
            for (int i = 0; i < 4; ++i) {
                int grow = 16 * w + quad * 4 + i;
                float v = fmaxf(acc[i] + bb, 0.0f);
                unsigned short h = f2bf(v);
                sh.HA[grow * ROWS + col] = h;
                sh.HA[64 * ROWS + grow * ROWS + col] = f2bf(v - bf2f(h));
            }
        }
    }

    // ---- layer 3: H2 @ W3 (bias deferred), masked strip-max ----
    {
        short8 aH[2], aL[2];
        aH[0] = *(const short8*)(sh.HA + arow * ROWS + quad * 8);
        aH[1] = *(const short8*)(sh.HA + arow * ROWS + 32 + quad * 8);
        aL[0] = *(const short8*)(sh.HA + 64 * ROWS + arow * ROWS + quad * 8);
        aL[1] = *(const short8*)(sh.HA + 64 * ROWS + arow * ROWS + 32 + quad * 8);
#pragma unroll
        for (int tile = 0; tile < 8; ++tile) {
            f32x4 acc = {};
#pragma unroll
            for (int ks = 0; ks < 2; ++ks) {
                short8 bH = wf8[2048 + ((tile * 2 + ks) * 2 + 0) * 64 + lane];
                short8 bL = wf8[2048 + ((tile * 2 + ks) * 2 + 1) * 64 + lane];
                acc = mfma16(aH[ks], bH, acc);
                acc = mfma16(aH[ks], bL, acc);
                acc = mfma16(aL[ks], bH, acc);
            }
            float mv = -1e10f;
#pragma unroll
            for (int i = 0; i < 4; ++i) {
                int grow = 16 * w + quad * 4 + i;   // neighbor index
                float v = (grow < V) ? acc[i] : -1e10f;
                mv = fmaxf(mv, v);
            }
            mv = fmaxf(mv, __shfl_xor(mv, 16));
            mv = fmaxf(mv, __shfl_xor(mv, 32));
            if (lane < 16) sh.red[w][tile * 16 + lane] = mv;
        }
    }
    __syncthreads();

    if (t < 128) {
        float v = fmaxf(fmaxf(sh.red[0][t], sh.red[1][t]),
                        fmaxf(sh.red[2][t], sh.red[3][t]));
        out[(size_t)bm * 128 + t] = v + b3[t];
    }
}

// ---------------------------------------------------------------------------
// Fused kernel (plain launch): blocks 0..7 = FPS producers, 8..255 = sa
// workers. 256 blocks always all-resident (>=1 block/CU on 256 CUs), and the
// worker spin has a hard poll budget + done[] flags + sweep kernel fallback:
// cannot deadlock, cannot fault, worst case degrades to serial speed.
// ---------------------------------------------------------------------------
union SharedMem {
    struct {
        float4 plds4[NN];                       // 64 KB
        int    chosen[MM];                      // 4 KB
        __align__(16) unsigned long long part[2][4];
    } fps;
    SaShared sa;
};

__global__ __launch_bounds__(256, 2) void fused_kernel(
    const float* __restrict__ x, const float* __restrict__ pos,
    int* __restrict__ idx_ws, unsigned int* __restrict__ ready,
    int* __restrict__ done, const unsigned short* __restrict__ wf,
    const float* __restrict__ b1, const float* __restrict__ b2,
    const float* __restrict__ b3, float* __restrict__ out)
{
    __shared__ SharedMem sh;
    const int t = threadIdx.x;

    if (blockIdx.x < BB) {
        // ================= FPS producer path =================
        __builtin_amdgcn_s_setprio(3);
        const int b = blockIdx.x;
        const float* P = pos + (size_t)b * NN * 3;
        for (int i = t; i < NN; i += 256) {
            float4 v;
            v.x = P[3 * i]; v.y = P[3 * i + 1]; v.z = P[3 * i + 2]; v.w = 0.0f;
            sh.fps.plds4[i] = v;
        }
        if (t == 0) {
            sh.fps.chosen[0] = 0;
            __hip_atomic_store(&idx_ws[b * MM], 0, __ATOMIC_RELAXED,
                               __HIP_MEMORY_SCOPE_AGENT);
        }
        __syncthreads();

        // pair s holds points i0 = t + 512*s (.x) and i0 + 256 (.y)
        f32x2 pxv[8], pyv[8], pzv[8], dminv[8];
#pragma unroll
        for (int s = 0; s < 8; ++s) {
            float4 a = sh.fps.plds4[t + 512 * s];
            float4 c = sh.fps.plds4[t + 512 * s + 256];
            pxv[s] = (f32x2){a.x, c.x};
            pyv[s] = (f32x2){a.y, c.y};
            pzv[s] = (f32x2){a.z, c.z};
            dminv[s] = (f32x2){1e10f, 1e10f};
        }

        int win = 0;
        for (int it = 1; it < MM; ++it) {
            float4 wc = sh.fps.plds4[win];
            const f32x2 lxv = (f32x2){wc.x, wc.x};
            const f32x2 lyv = (f32x2){wc.y, wc.y};
            const f32x2 lzv = (f32x2){wc.z, wc.z};
            float bv = -1.0f;
            int   bi = 0;
#pragma unroll
            for (int s = 0; s < 8; ++s) {
                f32x2 d;
                {
#pragma clang fp contract(off)
                    f32x2 dx = pxv[s] - lxv;
                    f32x2 dy = pyv[s] - lyv;
                    f32x2 dz = pzv[s] - lzv;
                    d = dx * dx + dy * dy + dz * dz;   // ((x2+y2)+z2), no FMA
                }
                float m0 = fminf(dminv[s].x, d.x);
                float m1 = fminf(dminv[s].y, d.y);
                dminv[s].x = m0;
                dminv[s].y = m1;
                // strict >: first-max priority; indices ascend (.x before .y)
                if (m0 > bv) { bv = m0; bi = t + 512 * s; }
                if (m1 > bv) { bv = m1; bi = t + 512 * s + 256; }
            }
            // d2 >= 0: float bits monotone as u32. max key = max d2, tie -> min idx.
            unsigned long long k =
                ((unsigned long long)__float_as_uint(bv) << 32) | (unsigned int)(~bi);
            k = dpp_maxkey<0x111>(k);  // row_shr:1
            k = dpp_maxkey<0x112>(k);  // row_shr:2
            k = dpp_maxkey<0x114>(k);  // row_shr:4
            k = dpp_maxkey<0x118>(k);  // row_shr:8
            k = dpp_maxkey<0x142>(k);  // row_bcast:15
            k = dpp_maxkey<0x143>(k);  // row_bcast:31  -> lane 63 has wave max
            if ((t & 63) == 63) sh.fps.part[it & 1][t >> 6] = k;
            __syncthreads();
            const ulonglong2* pp = (const ulonglong2*)&sh.fps.part[it & 1][0];
            ulonglong2 p01 = pp[0], p23 = pp[1];
            unsigned long long ka = p01.x > p01.y ? p01.x : p01.y;
            unsigned long long kb = p23.x > p23.y ? p23.x : p23.y;
            unsigned long long km = ka > kb ? ka : kb;
            win = (int)(~(unsigned int)km);
            if (t == 0) {
                sh.fps.chosen[it] = win;
                __hip_atomic_store(&idx_ws[b * MM + it], win, __ATOMIC_RELAXED,
                                   __HIP_MEMORY_SCOPE_AGENT);
                if ((it & 31) == 31)               // publish progress (release)
                    __hip_atomic_store(&ready[b], (unsigned int)(it + 1),
                                       __ATOMIC_RELEASE, __HIP_MEMORY_SCOPE_AGENT);
            }
            // parity buffer: no second barrier needed
        }
        __syncthreads();

        for (int m = t; m < MM; m += 256) {
            int mi = sh.fps.chosen[m];
            const int PO = BB * MM * 128;       // pos_out offset (floats)
            const int BO = PO + BB * MM * 3;    // batch_out offset
            int row = b * MM + m;
            float4 c = sh.fps.plds4[mi];
            out[PO + 3 * row + 0] = c.x;
            out[PO + 3 * row + 1] = c.y;
            out[PO + 3 * row + 2] = c.z;
            out[BO + row] = (float)b;
        }
        return;
    }

    // ================= sa worker path (bounded wait) =================
    int budget = 8000;   // sleep-polls; ~640+ cyc each -> hard bound ~2 ms
    for (int item = (int)blockIdx.x - BB; item < BB * MM; item += NWORK) {
        const int m  = item >> 3;             // centroid index (readiness order)
        const int b  = item & 7;              // cloud
        const int bm = b * MM + m;
        const float* P = pos + (size_t)b * NN * 3;

        if (t == 0) {
            const unsigned int need = (unsigned int)(m + 1);
            while (budget > 0 &&
                   __hip_atomic_load(&ready[b], __ATOMIC_ACQUIRE,
                                     __HIP_MEMORY_SCOPE_AGENT) < need) {
                __builtin_amdgcn_s_sleep(10);
                --budget;
            }
            sh.sa.ok = (__hip_atomic_load(&ready[b], __ATOMIC_ACQUIRE,
                                          __HIP_MEMORY_SCOPE_AGENT) >= need) ? 1 : 0;
        }
        __syncthreads();
        const int myok = sh.sa.ok;
        __syncthreads();   // close ok window before t0's next write
        if (!myok) continue;   // leave for sweep kernel

        const int ci = __hip_atomic_load(&idx_ws[bm], __ATOMIC_RELAXED,
                                         __HIP_MEMORY_SCOPE_AGENT) & (NN - 1);
        sa_process(sh.sa, x, P, wf, b1, b2, b3, out, bm, b, ci);
        if (t == 0)
            __hip_atomic_store(&done[bm], 1, __ATOMIC_RELAXED,
                               __HIP_MEMORY_SCOPE_AGENT);
        // visibility to sweep kernel is via kernel retirement (same stream)
    }
}

// ---------------------------------------------------------------------------
// Sweep kernel: one block per centroid; early-exit if the fused worker
// already produced it. Correct even if NOTHING overlapped.
// ---------------------------------------------------------------------------
__global__ __launch_bounds__(256, 4) void sweep_kernel(
    const float* __restrict__ x, const float* __restrict__ pos,
    const int* __restrict__ idx_ws, const int* __restrict__ done,
    const unsigned short* __restrict__ wf,
    const float* __restrict__ b1, const float* __restrict__ b2,
    const float* __restrict__ b3, float* __restrict__ out)
{
    __shared__ SaShared sh;
    const int bm = blockIdx.x;
    if (done[bm]) return;
    const int b = bm >> 10;
    const float* P = pos + (size_t)b * NN * 3;
    const int ci = idx_ws[bm] & (NN - 1);
    sa_process(sh, x, P, wf, b1, b2, b3, out, bm, b, ci);
}

extern "C" void kernel_launch(void* const* d_in, const int* in_sizes, int n_in,
                              void* d_out, int out_size, void* d_ws, size_t ws_size,
                              hipStream_t stream) {
    const float* x   = (const float*)d_in[0];
    const float* pos = (const float*)d_in[1];
    const float* W1 = (const float*)d_in[3];
    const float* b1 = (const float*)d_in[4];
    const float* W2 = (const float*)d_in[5];
    const float* b2 = (const float*)d_in[6];
    const float* W3 = (const float*)d_in[7];
    const float* b3 = (const float*)d_in[8];
    float* out    = (float*)d_out;
    int*   idx_ws = (int*)d_ws;                                    // [0, 32768)
    unsigned short* wf = (unsigned short*)((char*)d_ws + 32768);   // [32768, 98304)
    unsigned int* ready = (unsigned int*)((char*)d_ws + 98304);    // [98304, 98336)
    int* done = (int*)((char*)d_ws + 98368);                       // [98368, 131136)

    hipMemsetAsync((char*)d_ws + 98304, 0, 131136 - 98304, stream);
    hipLaunchKernelGGL(prep_kernel, dim3(16), dim3(256), 0, stream, W1, W2, W3, wf);
    hipLaunchKernelGGL(fused_kernel, dim3(GRID), dim3(256), 0, stream,
                       x, pos, idx_ws, ready, done, wf, b1, b2, b3, out);
    hipLaunchKernelGGL(sweep_kernel, dim3(BB * MM), dim3(256), 0, stream,
                       x, pos, idx_ws, done, wf, b1, b2, b3, out);
}